// Round 1
// baseline (740.415 us; speedup 1.0000x reference)
//
#include <hip/hip_runtime.h>
#include <math.h>

#define NEG_SLOPE 0.2f

// ---------------- CSR build ----------------
__global__ void zero_i32_k(int* __restrict__ p, int n) {
  int i = blockIdx.x * 256 + threadIdx.x;
  if (i < n) p[i] = 0;
}

__global__ void count_k(const int* __restrict__ ei, int E, int N, int* __restrict__ deg) {
  int i = blockIdx.x * 256 + threadIdx.x;
  if (i >= E + N) return;
  int dst = (i < E) ? ei[E + i] : (i - E);
  atomicAdd(&deg[dst], 1);
}

// single-block exclusive scan over N counts -> off[0..N]
__global__ __launch_bounds__(1024) void scan_k(const int* __restrict__ deg, int* __restrict__ off, int N) {
  __shared__ int buf[1024];
  __shared__ int s_carry;
  int t = threadIdx.x;
  if (t == 0) s_carry = 0;
  __syncthreads();
  for (int base = 0; base < N; base += 1024) {
    int v = (base + t < N) ? deg[base + t] : 0;
    buf[t] = v;
    __syncthreads();
    for (int ofs = 1; ofs < 1024; ofs <<= 1) {
      int add = (t >= ofs) ? buf[t - ofs] : 0;
      __syncthreads();
      buf[t] += add;
      __syncthreads();
    }
    int c = s_carry;
    if (base + t < N) off[base + t] = c + buf[t] - v;   // exclusive
    __syncthreads();
    if (t == 0) s_carry = c + buf[1023];
    __syncthreads();
  }
  if (t == 0) off[N] = s_carry;
}

__global__ void copy_i32_k(const int* __restrict__ a, int* __restrict__ b, int n) {
  int i = blockIdx.x * 256 + threadIdx.x;
  if (i < n) b[i] = a[i];
}

__global__ void fill_k(const int* __restrict__ ei, int E, int N,
                       int* __restrict__ cursor, int* __restrict__ csr) {
  int i = blockIdx.x * 256 + threadIdx.x;
  if (i >= E + N) return;
  int src, dst;
  if (i < E) { src = ei[i]; dst = ei[E + i]; }
  else       { src = i - E; dst = src; }
  int pos = atomicAdd(&cursor[dst], 1);
  csr[pos] = src;
}

// ---------------- GEMM1: h1[N,512] = x[N,128] @ W1[512,128]^T ----------------
// 64x64 tile, full K=128 staged, XOR-swizzled LDS, 4x4 per thread.
__global__ __launch_bounds__(256) void gemm1_k(const float* __restrict__ x,
                                               const float* __restrict__ W1,
                                               float* __restrict__ h1, int N) {
  __shared__ float As[64 * 128];
  __shared__ float Bs[64 * 128];
  const int tid = threadIdx.x;
  const int bm = blockIdx.x * 64;
  const int bn = blockIdx.y * 64;

#pragma unroll
  for (int i = 0; i < 8; ++i) {
    int f = tid + 256 * i;
    int r = f >> 5, c4 = f & 31;
    int sw = ((c4 ^ ((r >> 2) & 7)) << 2);
    float4 av = make_float4(0.f, 0.f, 0.f, 0.f);
    if (bm + r < N) av = *(const float4*)(x + (size_t)(bm + r) * 128 + (c4 << 2));
    *(float4*)(As + r * 128 + sw) = av;
    float4 bv = *(const float4*)(W1 + (size_t)(bn + r) * 128 + (c4 << 2));
    *(float4*)(Bs + r * 128 + sw) = bv;
  }
  __syncthreads();

  const int ty = tid >> 4, tx = tid & 15;
  float acc[4][4];
#pragma unroll
  for (int j = 0; j < 4; ++j)
#pragma unroll
    for (int i = 0; i < 4; ++i) acc[j][i] = 0.f;

  for (int k4 = 0; k4 < 32; ++k4) {
    float4 a[4], b[4];
#pragma unroll
    for (int j = 0; j < 4; ++j) {
      int r = ty * 4 + j;
      a[j] = *(const float4*)(As + r * 128 + ((k4 ^ ((r >> 2) & 7)) << 2));
    }
#pragma unroll
    for (int i = 0; i < 4; ++i) {
      int r = tx * 4 + i;
      b[i] = *(const float4*)(Bs + r * 128 + ((k4 ^ ((r >> 2) & 7)) << 2));
    }
#pragma unroll
    for (int j = 0; j < 4; ++j)
#pragma unroll
      for (int i = 0; i < 4; ++i) {
        acc[j][i] = fmaf(a[j].x, b[i].x, acc[j][i]);
        acc[j][i] = fmaf(a[j].y, b[i].y, acc[j][i]);
        acc[j][i] = fmaf(a[j].z, b[i].z, acc[j][i]);
        acc[j][i] = fmaf(a[j].w, b[i].w, acc[j][i]);
      }
  }

#pragma unroll
  for (int j = 0; j < 4; ++j) {
    int row = bm + ty * 4 + j;
    if (row < N) {
      float4 o = make_float4(acc[j][0], acc[j][1], acc[j][2], acc[j][3]);
      *(float4*)(h1 + (size_t)row * 512 + bn + tx * 4) = o;
    }
  }
}

// ---------------- per-node attention halves, layer1 ----------------
// as1[n,h] = sum_c h1[n,h,c]*a_src1[h,c] ; ad1 likewise. One wave per node.
__global__ __launch_bounds__(256) void alpha1_k(const float* __restrict__ h1,
                                                const float* __restrict__ a_src,
                                                const float* __restrict__ a_dst,
                                                float* __restrict__ as1,
                                                float* __restrict__ ad1, int N) {
  int n = blockIdx.x * 4 + (threadIdx.x >> 6);
  int lane = threadIdx.x & 63;
  if (n >= N) return;
  int cb = lane * 8;
  const float4* hp = (const float4*)(h1 + (size_t)n * 512 + cb);
  float4 v0 = hp[0], v1 = hp[1];
  const float4* sp = (const float4*)(a_src + cb);
  const float4* dp = (const float4*)(a_dst + cb);
  float4 s0 = sp[0], s1 = sp[1], d0 = dp[0], d1 = dp[1];
  float s = v0.x * s0.x + v0.y * s0.y + v0.z * s0.z + v0.w * s0.w +
            v1.x * s1.x + v1.y * s1.y + v1.z * s1.z + v1.w * s1.w;
  float d = v0.x * d0.x + v0.y * d0.y + v0.z * d0.z + v0.w * d0.w +
            v1.x * d1.x + v1.y * d1.y + v1.z * d1.z + v1.w * d1.w;
#pragma unroll
  for (int ofs = 1; ofs < 16; ofs <<= 1) {
    s += __shfl_xor(s, ofs);
    d += __shfl_xor(d, ofs);
  }
  if ((lane & 15) == 0) {
    int h = lane >> 4;
    as1[(size_t)n * 4 + h] = s;
    ad1[(size_t)n * 4 + h] = d;
  }
}

// ---------------- layer-1 softmax + aggregate + bias + ELU ----------------
// One wave per destination node; lane owns 8 contiguous channels of the 512.
__global__ __launch_bounds__(256) void agg1_k(const float* __restrict__ h1,
                                              const float* __restrict__ as1,
                                              const float* __restrict__ ad1,
                                              const int* __restrict__ off,
                                              const int* __restrict__ csr,
                                              const float* __restrict__ b1,
                                              float* __restrict__ helu, int N) {
  int n = blockIdx.x * 4 + (threadIdx.x >> 6);
  int lane = threadIdx.x & 63;
  if (n >= N) return;
  int row = off[n], end = off[n + 1];
  float4 adn = *(const float4*)(ad1 + (size_t)n * 4);

  // pass 1: per-head max (edge-parallel across lanes)
  float m0 = -1e30f, m1 = -1e30f, m2 = -1e30f, m3 = -1e30f;
  for (int idx = row + lane; idx < end; idx += 64) {
    int s = csr[idx];
    float4 av = *(const float4*)(as1 + (size_t)s * 4);
    float e0 = av.x + adn.x; e0 = e0 > 0.f ? e0 : NEG_SLOPE * e0; m0 = fmaxf(m0, e0);
    float e1 = av.y + adn.y; e1 = e1 > 0.f ? e1 : NEG_SLOPE * e1; m1 = fmaxf(m1, e1);
    float e2 = av.z + adn.z; e2 = e2 > 0.f ? e2 : NEG_SLOPE * e2; m2 = fmaxf(m2, e2);
    float e3 = av.w + adn.w; e3 = e3 > 0.f ? e3 : NEG_SLOPE * e3; m3 = fmaxf(m3, e3);
  }
#pragma unroll
  for (int ofs = 1; ofs < 64; ofs <<= 1) {
    m0 = fmaxf(m0, __shfl_xor(m0, ofs));
    m1 = fmaxf(m1, __shfl_xor(m1, ofs));
    m2 = fmaxf(m2, __shfl_xor(m2, ofs));
    m3 = fmaxf(m3, __shfl_xor(m3, ofs));
  }

  int hh = lane >> 4;                       // this lane's head
  float mh  = hh == 0 ? m0 : hh == 1 ? m1 : hh == 2 ? m2 : m3;
  float adh = hh == 0 ? adn.x : hh == 1 ? adn.y : hh == 2 ? adn.z : adn.w;
  int cb = lane * 8;

  // pass 2: exp / sum / weighted gather-accumulate (channel-parallel)
  float a0 = 0.f, a1 = 0.f, a2 = 0.f, a3 = 0.f, a4 = 0.f, a5 = 0.f, a6 = 0.f, a7 = 0.f;
  float z = 0.f;
  for (int idx = row; idx < end; ++idx) {
    int s = csr[idx];
    float e = as1[(size_t)s * 4 + hh] + adh;
    e = e > 0.f ? e : NEG_SLOPE * e;
    float p = __expf(e - mh);
    z += p;
    const float4* hp = (const float4*)(h1 + (size_t)s * 512 + cb);
    float4 v0 = hp[0], v1 = hp[1];
    a0 = fmaf(p, v0.x, a0); a1 = fmaf(p, v0.y, a1);
    a2 = fmaf(p, v0.z, a2); a3 = fmaf(p, v0.w, a3);
    a4 = fmaf(p, v1.x, a4); a5 = fmaf(p, v1.y, a5);
    a6 = fmaf(p, v1.z, a6); a7 = fmaf(p, v1.w, a7);
  }
  float inv = 1.f / z;
  const float4* bp = (const float4*)(b1 + cb);
  float4 bb0 = bp[0], bb1 = bp[1];
  float4 r0, r1;
  float o;
  o = fmaf(a0, inv, bb0.x); r0.x = o > 0.f ? o : expm1f(o);
  o = fmaf(a1, inv, bb0.y); r0.y = o > 0.f ? o : expm1f(o);
  o = fmaf(a2, inv, bb0.z); r0.z = o > 0.f ? o : expm1f(o);
  o = fmaf(a3, inv, bb0.w); r0.w = o > 0.f ? o : expm1f(o);
  o = fmaf(a4, inv, bb1.x); r1.x = o > 0.f ? o : expm1f(o);
  o = fmaf(a5, inv, bb1.y); r1.y = o > 0.f ? o : expm1f(o);
  o = fmaf(a6, inv, bb1.z); r1.z = o > 0.f ? o : expm1f(o);
  o = fmaf(a7, inv, bb1.w); r1.w = o > 0.f ? o : expm1f(o);
  float4* op = (float4*)(helu + (size_t)n * 512 + cb);
  op[0] = r0;
  op[1] = r1;
}

// ---------------- GEMM2 + layer-2 attention halves ----------------
// h2[N,8] = helu[N,512] @ W2[8,512]^T ; one wave per node, W2 in LDS.
__global__ __launch_bounds__(256) void gemm2_k(const float* __restrict__ helu,
                                               const float* __restrict__ W2,
                                               const float* __restrict__ a_src2,
                                               const float* __restrict__ a_dst2,
                                               float* __restrict__ h2,
                                               float* __restrict__ as2,
                                               float* __restrict__ ad2, int N) {
  __shared__ float Ws[8 * 512];
  for (int i = threadIdx.x; i < 8 * 512; i += 256) Ws[i] = W2[i];
  __syncthreads();
  int n = blockIdx.x * 4 + (threadIdx.x >> 6);
  int lane = threadIdx.x & 63;
  if (n >= N) return;
  float acc[8];
#pragma unroll
  for (int o = 0; o < 8; ++o) acc[o] = 0.f;
  const float* hp = helu + (size_t)n * 512;
#pragma unroll
  for (int t = 0; t < 8; ++t) {
    int c = lane + 64 * t;
    float xv = hp[c];
#pragma unroll
    for (int o = 0; o < 8; ++o) acc[o] = fmaf(xv, Ws[o * 512 + c], acc[o]);
  }
#pragma unroll
  for (int ofs = 1; ofs < 64; ofs <<= 1) {
#pragma unroll
    for (int o = 0; o < 8; ++o) acc[o] += __shfl_xor(acc[o], ofs);
  }
  if (lane == 0) {
    float* ho = h2 + (size_t)n * 8;
#pragma unroll
    for (int o = 0; o < 8; ++o) ho[o] = acc[o];
#pragma unroll
    for (int h = 0; h < 4; ++h) {
      as2[(size_t)n * 4 + h] = acc[2 * h] * a_src2[2 * h] + acc[2 * h + 1] * a_src2[2 * h + 1];
      ad2[(size_t)n * 4 + h] = acc[2 * h] * a_dst2[2 * h] + acc[2 * h + 1] * a_dst2[2 * h + 1];
    }
  }
}

// ---------------- layer-2 softmax + aggregate + head-mean + bias ----------------
// One wave per destination node, edge-parallel across lanes.
__global__ __launch_bounds__(256) void agg2_k(const float* __restrict__ h2,
                                              const float* __restrict__ as2,
                                              const float* __restrict__ ad2,
                                              const int* __restrict__ off,
                                              const int* __restrict__ csr,
                                              const float* __restrict__ b2,
                                              float* __restrict__ out, int N) {
  int n = blockIdx.x * 4 + (threadIdx.x >> 6);
  int lane = threadIdx.x & 63;
  if (n >= N) return;
  int row = off[n], end = off[n + 1];
  float4 adn = *(const float4*)(ad2 + (size_t)n * 4);

  float m0 = -1e30f, m1 = -1e30f, m2 = -1e30f, m3 = -1e30f;
  for (int idx = row + lane; idx < end; idx += 64) {
    int s = csr[idx];
    float4 av = *(const float4*)(as2 + (size_t)s * 4);
    float e0 = av.x + adn.x; e0 = e0 > 0.f ? e0 : NEG_SLOPE * e0; m0 = fmaxf(m0, e0);
    float e1 = av.y + adn.y; e1 = e1 > 0.f ? e1 : NEG_SLOPE * e1; m1 = fmaxf(m1, e1);
    float e2 = av.z + adn.z; e2 = e2 > 0.f ? e2 : NEG_SLOPE * e2; m2 = fmaxf(m2, e2);
    float e3 = av.w + adn.w; e3 = e3 > 0.f ? e3 : NEG_SLOPE * e3; m3 = fmaxf(m3, e3);
  }
#pragma unroll
  for (int ofs = 1; ofs < 64; ofs <<= 1) {
    m0 = fmaxf(m0, __shfl_xor(m0, ofs));
    m1 = fmaxf(m1, __shfl_xor(m1, ofs));
    m2 = fmaxf(m2, __shfl_xor(m2, ofs));
    m3 = fmaxf(m3, __shfl_xor(m3, ofs));
  }

  float z0 = 0.f, z1 = 0.f, z2 = 0.f, z3 = 0.f;
  float c0 = 0.f, c1 = 0.f, c2 = 0.f, c3 = 0.f, c4 = 0.f, c5 = 0.f, c6 = 0.f, c7 = 0.f;
  for (int idx = row + lane; idx < end; idx += 64) {
    int s = csr[idx];
    float4 av = *(const float4*)(as2 + (size_t)s * 4);
    const float4* vp = (const float4*)(h2 + (size_t)s * 8);
    float4 v0 = vp[0], v1 = vp[1];
    float e, p;
    e = av.x + adn.x; e = e > 0.f ? e : NEG_SLOPE * e; p = __expf(e - m0); z0 += p;
    c0 = fmaf(p, v0.x, c0); c1 = fmaf(p, v0.y, c1);
    e = av.y + adn.y; e = e > 0.f ? e : NEG_SLOPE * e; p = __expf(e - m1); z1 += p;
    c2 = fmaf(p, v0.z, c2); c3 = fmaf(p, v0.w, c3);
    e = av.z + adn.z; e = e > 0.f ? e : NEG_SLOPE * e; p = __expf(e - m2); z2 += p;
    c4 = fmaf(p, v1.x, c4); c5 = fmaf(p, v1.y, c5);
    e = av.w + adn.w; e = e > 0.f ? e : NEG_SLOPE * e; p = __expf(e - m3); z3 += p;
    c6 = fmaf(p, v1.z, c6); c7 = fmaf(p, v1.w, c7);
  }
#pragma unroll
  for (int ofs = 1; ofs < 64; ofs <<= 1) {
    z0 += __shfl_xor(z0, ofs); z1 += __shfl_xor(z1, ofs);
    z2 += __shfl_xor(z2, ofs); z3 += __shfl_xor(z3, ofs);
    c0 += __shfl_xor(c0, ofs); c1 += __shfl_xor(c1, ofs);
    c2 += __shfl_xor(c2, ofs); c3 += __shfl_xor(c3, ofs);
    c4 += __shfl_xor(c4, ofs); c5 += __shfl_xor(c5, ofs);
    c6 += __shfl_xor(c6, ofs); c7 += __shfl_xor(c7, ofs);
  }
  if (lane == 0) {
    float o0 = 0.25f * (c0 / z0 + c2 / z1 + c4 / z2 + c6 / z3) + b2[0];
    float o1 = 0.25f * (c1 / z0 + c3 / z1 + c5 / z2 + c7 / z3) + b2[1];
    out[(size_t)n * 2]     = o0;
    out[(size_t)n * 2 + 1] = o1;
  }
}

// ---------------- host ----------------
extern "C" void kernel_launch(void* const* d_in, const int* in_sizes, int n_in,
                              void* d_out, int out_size, void* d_ws, size_t ws_size,
                              hipStream_t stream) {
  const float* x      = (const float*)d_in[0];
  const int*   ei     = (const int*)d_in[1];
  const float* W1     = (const float*)d_in[2];
  const float* a_src1 = (const float*)d_in[3];
  const float* a_dst1 = (const float*)d_in[4];
  const float* b1     = (const float*)d_in[5];
  const float* W2     = (const float*)d_in[6];
  const float* a_src2 = (const float*)d_in[7];
  const float* a_dst2 = (const float*)d_in[8];
  const float* b2     = (const float*)d_in[9];
  float* out = (float*)d_out;

  const int N = in_sizes[0] / 128;
  const int E = in_sizes[1] / 2;
  const int TOT = E + N;

  char* ws = (char*)d_ws;
  auto alloc = [&](size_t bytes) {
    char* p = ws;
    ws += (bytes + 511) & ~(size_t)511;
    return p;
  };
  float* h1     = (float*)alloc((size_t)N * 512 * 4);
  float* helu   = (float*)alloc((size_t)N * 512 * 4);
  float* as1    = (float*)alloc((size_t)N * 4 * 4);
  float* ad1    = (float*)alloc((size_t)N * 4 * 4);
  float* h2     = (float*)alloc((size_t)N * 8 * 4);
  float* as2    = (float*)alloc((size_t)N * 4 * 4);
  float* ad2    = (float*)alloc((size_t)N * 4 * 4);
  int*   deg    = (int*)alloc((size_t)N * 4);
  int*   off    = (int*)alloc((size_t)(N + 1) * 4);
  int*   cursor = (int*)alloc((size_t)N * 4);
  int*   csr    = (int*)alloc((size_t)TOT * 4);

  const int eb    = (TOT + 255) / 256;
  const int nb256 = (N + 255) / 256;
  const int nwb   = (N + 3) / 4;      // 4 waves (nodes) per 256-thread block

  zero_i32_k<<<nb256, 256, 0, stream>>>(deg, N);
  count_k<<<eb, 256, 0, stream>>>(ei, E, N, deg);
  scan_k<<<1, 1024, 0, stream>>>(deg, off, N);
  copy_i32_k<<<nb256, 256, 0, stream>>>(off, cursor, N);
  fill_k<<<eb, 256, 0, stream>>>(ei, E, N, cursor, csr);

  gemm1_k<<<dim3((N + 63) / 64, 512 / 64), 256, 0, stream>>>(x, W1, h1, N);
  alpha1_k<<<nwb, 256, 0, stream>>>(h1, a_src1, a_dst1, as1, ad1, N);
  agg1_k<<<nwb, 256, 0, stream>>>(h1, as1, ad1, off, csr, b1, helu, N);
  gemm2_k<<<nwb, 256, 0, stream>>>(helu, W2, a_src2, a_dst2, h2, as2, ad2, N);
  agg2_k<<<nwb, 256, 0, stream>>>(h2, as2, ad2, off, csr, b2, out, N);
}

// Round 4
// 594.248 us; speedup vs baseline: 1.2460x; 1.2460x over previous
//
#include <hip/hip_runtime.h>
#include <math.h>

#define NEG_SLOPE 0.2f

// ---------------- CSR build ----------------
__global__ void count_k(const int* __restrict__ ei, int E, int N, int* __restrict__ deg) {
  int i = blockIdx.x * 256 + threadIdx.x;
  if (i >= E + N) return;
  int dst = (i < E) ? ei[E + i] : (i - E);
  atomicAdd(&deg[dst], 1);
}

// hierarchical scan: per-block (256) exclusive scan + block sums
__global__ __launch_bounds__(256) void scan1_k(const int* __restrict__ deg, int* __restrict__ off,
                                               int* __restrict__ sums, int N) {
  __shared__ int buf[256];
  int t = threadIdx.x, i = blockIdx.x * 256 + t;
  int v = (i < N) ? deg[i] : 0;
  buf[t] = v;
  __syncthreads();
#pragma unroll
  for (int ofs = 1; ofs < 256; ofs <<= 1) {
    int add = (t >= ofs) ? buf[t - ofs] : 0;
    __syncthreads();
    buf[t] += add;
    __syncthreads();
  }
  if (i < N) off[i] = buf[t] - v;           // local exclusive
  if (t == 255) sums[blockIdx.x] = buf[t];  // block total
}

__global__ __launch_bounds__(1024) void scan2_k(int* __restrict__ sums, int nb) {
  __shared__ int buf[1024];
  int t = threadIdx.x;
  int v = (t < nb) ? sums[t] : 0;
  buf[t] = v;
  __syncthreads();
#pragma unroll
  for (int ofs = 1; ofs < 1024; ofs <<= 1) {
    int add = (t >= ofs) ? buf[t - ofs] : 0;
    __syncthreads();
    buf[t] += add;
    __syncthreads();
  }
  if (t < nb) sums[t] = buf[t] - v;          // exclusive block offsets
}

__global__ __launch_bounds__(256) void scan3_k(int* __restrict__ off, const int* __restrict__ sums,
                                               int* __restrict__ cursor, int N, int TOT) {
  int i = blockIdx.x * 256 + threadIdx.x;
  if (i < N) {
    int v = off[i] + sums[blockIdx.x];
    off[i] = v;
    cursor[i] = v;
  }
  if (i == 0) off[N] = TOT;
}

__global__ void fill_k(const int* __restrict__ ei, int E, int N,
                       int* __restrict__ cursor, int* __restrict__ csr) {
  int i = blockIdx.x * 256 + threadIdx.x;
  if (i >= E + N) return;
  int src, dst;
  if (i < E) { src = ei[i]; dst = ei[E + i]; }
  else       { src = i - E; dst = src; }
  int pos = atomicAdd(&cursor[dst], 1);
  csr[pos] = src;
}

// ---------------- GEMM1 (+fused per-node attention halves) ----------------
// h1[N,512] = x[N,128] @ W1[512,128]^T ; 64x64 tile, XOR-swizzled LDS, 4x4/thread.
// Epilogue: each block's 64-col slice lies within ONE head -> partial dots with
// a_src1/a_dst1, shfl-reduce over tx, atomicAdd into as1/ad1 (pre-zeroed).
__global__ __launch_bounds__(256) void gemm1_k(const float* __restrict__ x,
                                               const float* __restrict__ W1,
                                               const float* __restrict__ a_src1,
                                               const float* __restrict__ a_dst1,
                                               float* __restrict__ h1,
                                               float* __restrict__ as1,
                                               float* __restrict__ ad1, int N) {
  __shared__ float As[64 * 128];
  __shared__ float Bs[64 * 128];
  const int tid = threadIdx.x;
  const int bm = blockIdx.x * 64;
  const int bn = blockIdx.y * 64;

#pragma unroll
  for (int i = 0; i < 8; ++i) {
    int f = tid + 256 * i;
    int r = f >> 5, c4 = f & 31;
    int sw = ((c4 ^ ((r >> 2) & 7)) << 2);
    float4 av = make_float4(0.f, 0.f, 0.f, 0.f);
    if (bm + r < N) av = *(const float4*)(x + (size_t)(bm + r) * 128 + (c4 << 2));
    *(float4*)(As + r * 128 + sw) = av;
    float4 bv = *(const float4*)(W1 + (size_t)(bn + r) * 128 + (c4 << 2));
    *(float4*)(Bs + r * 128 + sw) = bv;
  }
  __syncthreads();

  const int ty = tid >> 4, tx = tid & 15;
  float acc[4][4];
#pragma unroll
  for (int j = 0; j < 4; ++j)
#pragma unroll
    for (int i = 0; i < 4; ++i) acc[j][i] = 0.f;

  for (int k4 = 0; k4 < 32; ++k4) {
    float4 a[4], b[4];
#pragma unroll
    for (int j = 0; j < 4; ++j) {
      int r = ty * 4 + j;
      a[j] = *(const float4*)(As + r * 128 + ((k4 ^ ((r >> 2) & 7)) << 2));
    }
#pragma unroll
    for (int i = 0; i < 4; ++i) {
      int r = tx * 4 + i;
      b[i] = *(const float4*)(Bs + r * 128 + ((k4 ^ ((r >> 2) & 7)) << 2));
    }
#pragma unroll
    for (int j = 0; j < 4; ++j)
#pragma unroll
      for (int i = 0; i < 4; ++i) {
        acc[j][i] = fmaf(a[j].x, b[i].x, acc[j][i]);
        acc[j][i] = fmaf(a[j].y, b[i].y, acc[j][i]);
        acc[j][i] = fmaf(a[j].z, b[i].z, acc[j][i]);
        acc[j][i] = fmaf(a[j].w, b[i].w, acc[j][i]);
      }
  }

#pragma unroll
  for (int j = 0; j < 4; ++j) {
    int row = bm + ty * 4 + j;
    if (row < N) {
      float4 o = make_float4(acc[j][0], acc[j][1], acc[j][2], acc[j][3]);
      *(float4*)(h1 + (size_t)row * 512 + bn + tx * 4) = o;
    }
  }

  // fused attention halves
  const int head = bn >> 7;
  const int aoff = (bn & 127) + tx * 4;
  float4 av = *(const float4*)(a_src1 + head * 128 + aoff);
  float4 dv = *(const float4*)(a_dst1 + head * 128 + aoff);
#pragma unroll
  for (int j = 0; j < 4; ++j) {
    float sp = acc[j][0] * av.x + acc[j][1] * av.y + acc[j][2] * av.z + acc[j][3] * av.w;
    float dp = acc[j][0] * dv.x + acc[j][1] * dv.y + acc[j][2] * dv.z + acc[j][3] * dv.w;
#pragma unroll
    for (int ofs = 1; ofs < 16; ofs <<= 1) {
      sp += __shfl_xor(sp, ofs);
      dp += __shfl_xor(dp, ofs);
    }
    int row = bm + ty * 4 + j;
    if (tx == 0 && row < N) {
      atomicAdd(&as1[(size_t)row * 4 + head], sp);
      atomicAdd(&ad1[(size_t)row * 4 + head], dp);
    }
  }
}

// ---------------- layer-1 softmax+aggregate+bias+ELU, fused with GEMM2 ----------------
// One wave per dst node; lane owns 8 contiguous channels. Pass2 unrolled x4 for MLP.
// Epilogue computes h2 = helu @ W2^T and layer-2 attention halves in-wave.
__global__ __launch_bounds__(256) void agg1_k(const float* __restrict__ h1,
                                              const float* __restrict__ as1,
                                              const float* __restrict__ ad1,
                                              const int* __restrict__ off,
                                              const int* __restrict__ csr,
                                              const float* __restrict__ b1,
                                              const float* __restrict__ W2,
                                              const float* __restrict__ a_src2,
                                              const float* __restrict__ a_dst2,
                                              float* __restrict__ h2,
                                              float* __restrict__ as2,
                                              float* __restrict__ ad2, int N) {
  int n = blockIdx.x * 4 + (threadIdx.x >> 6);
  int lane = threadIdx.x & 63;
  if (n >= N) return;
  int row = off[n], end = off[n + 1];
  float4 adn = *(const float4*)(ad1 + (size_t)n * 4);

  // pass 1: per-head max (edge-parallel across lanes)
  float m0 = -1e30f, m1 = -1e30f, m2 = -1e30f, m3 = -1e30f;
  for (int idx = row + lane; idx < end; idx += 64) {
    int s = csr[idx];
    float4 av = *(const float4*)(as1 + (size_t)s * 4);
    float e0 = av.x + adn.x; e0 = e0 > 0.f ? e0 : NEG_SLOPE * e0; m0 = fmaxf(m0, e0);
    float e1 = av.y + adn.y; e1 = e1 > 0.f ? e1 : NEG_SLOPE * e1; m1 = fmaxf(m1, e1);
    float e2 = av.z + adn.z; e2 = e2 > 0.f ? e2 : NEG_SLOPE * e2; m2 = fmaxf(m2, e2);
    float e3 = av.w + adn.w; e3 = e3 > 0.f ? e3 : NEG_SLOPE * e3; m3 = fmaxf(m3, e3);
  }
#pragma unroll
  for (int ofs = 1; ofs < 64; ofs <<= 1) {
    m0 = fmaxf(m0, __shfl_xor(m0, ofs));
    m1 = fmaxf(m1, __shfl_xor(m1, ofs));
    m2 = fmaxf(m2, __shfl_xor(m2, ofs));
    m3 = fmaxf(m3, __shfl_xor(m3, ofs));
  }

  int hh = lane >> 4;
  float mh  = hh == 0 ? m0 : hh == 1 ? m1 : hh == 2 ? m2 : m3;
  float adh = hh == 0 ? adn.x : hh == 1 ? adn.y : hh == 2 ? adn.z : adn.w;
  int cb = lane * 8;

  // pass 2: exp/sum/weighted gather-accumulate, unrolled x4 for MLP
  float a0 = 0.f, a1 = 0.f, a2 = 0.f, a3 = 0.f, a4 = 0.f, a5 = 0.f, a6 = 0.f, a7 = 0.f;
  float z = 0.f;
  int idx = row;
  for (; idx + 4 <= end; idx += 4) {
    int s0 = csr[idx], s1 = csr[idx + 1], s2 = csr[idx + 2], s3 = csr[idx + 3];
    float e0 = as1[(size_t)s0 * 4 + hh];
    float e1 = as1[(size_t)s1 * 4 + hh];
    float e2 = as1[(size_t)s2 * 4 + hh];
    float e3 = as1[(size_t)s3 * 4 + hh];
    const float4* p0 = (const float4*)(h1 + (size_t)s0 * 512 + cb);
    const float4* p1 = (const float4*)(h1 + (size_t)s1 * 512 + cb);
    const float4* p2 = (const float4*)(h1 + (size_t)s2 * 512 + cb);
    const float4* p3 = (const float4*)(h1 + (size_t)s3 * 512 + cb);
    float4 u00 = p0[0], u01 = p0[1];
    float4 u10 = p1[0], u11 = p1[1];
    float4 u20 = p2[0], u21 = p2[1];
    float4 u30 = p3[0], u31 = p3[1];
    e0 += adh; e0 = e0 > 0.f ? e0 : NEG_SLOPE * e0; float q0 = __expf(e0 - mh);
    e1 += adh; e1 = e1 > 0.f ? e1 : NEG_SLOPE * e1; float q1 = __expf(e1 - mh);
    e2 += adh; e2 = e2 > 0.f ? e2 : NEG_SLOPE * e2; float q2 = __expf(e2 - mh);
    e3 += adh; e3 = e3 > 0.f ? e3 : NEG_SLOPE * e3; float q3 = __expf(e3 - mh);
    z += q0 + q1 + q2 + q3;
    a0 = fmaf(q0, u00.x, a0); a1 = fmaf(q0, u00.y, a1);
    a2 = fmaf(q0, u00.z, a2); a3 = fmaf(q0, u00.w, a3);
    a4 = fmaf(q0, u01.x, a4); a5 = fmaf(q0, u01.y, a5);
    a6 = fmaf(q0, u01.z, a6); a7 = fmaf(q0, u01.w, a7);
    a0 = fmaf(q1, u10.x, a0); a1 = fmaf(q1, u10.y, a1);
    a2 = fmaf(q1, u10.z, a2); a3 = fmaf(q1, u10.w, a3);
    a4 = fmaf(q1, u11.x, a4); a5 = fmaf(q1, u11.y, a5);
    a6 = fmaf(q1, u11.z, a6); a7 = fmaf(q1, u11.w, a7);
    a0 = fmaf(q2, u20.x, a0); a1 = fmaf(q2, u20.y, a1);
    a2 = fmaf(q2, u20.z, a2); a3 = fmaf(q2, u20.w, a3);
    a4 = fmaf(q2, u21.x, a4); a5 = fmaf(q2, u21.y, a5);
    a6 = fmaf(q2, u21.z, a6); a7 = fmaf(q2, u21.w, a7);
    a0 = fmaf(q3, u30.x, a0); a1 = fmaf(q3, u30.y, a1);
    a2 = fmaf(q3, u30.z, a2); a3 = fmaf(q3, u30.w, a3);
    a4 = fmaf(q3, u31.x, a4); a5 = fmaf(q3, u31.y, a5);
    a6 = fmaf(q3, u31.z, a6); a7 = fmaf(q3, u31.w, a7);
  }
  for (; idx < end; ++idx) {
    int s = csr[idx];
    float e = as1[(size_t)s * 4 + hh] + adh;
    e = e > 0.f ? e : NEG_SLOPE * e;
    float q = __expf(e - mh);
    z += q;
    const float4* hp = (const float4*)(h1 + (size_t)s * 512 + cb);
    float4 v0 = hp[0], v1 = hp[1];
    a0 = fmaf(q, v0.x, a0); a1 = fmaf(q, v0.y, a1);
    a2 = fmaf(q, v0.z, a2); a3 = fmaf(q, v0.w, a3);
    a4 = fmaf(q, v1.x, a4); a5 = fmaf(q, v1.y, a5);
    a6 = fmaf(q, v1.z, a6); a7 = fmaf(q, v1.w, a7);
  }

  // epilogue: bias + ELU -> helu (in regs), then fused GEMM2 + layer-2 halves
  float inv = 1.f / z;
  const float4* bp = (const float4*)(b1 + cb);
  float4 bb0 = bp[0], bb1 = bp[1];
  float hl[8];
  float o;
  o = fmaf(a0, inv, bb0.x); hl[0] = o > 0.f ? o : expm1f(o);
  o = fmaf(a1, inv, bb0.y); hl[1] = o > 0.f ? o : expm1f(o);
  o = fmaf(a2, inv, bb0.z); hl[2] = o > 0.f ? o : expm1f(o);
  o = fmaf(a3, inv, bb0.w); hl[3] = o > 0.f ? o : expm1f(o);
  o = fmaf(a4, inv, bb1.x); hl[4] = o > 0.f ? o : expm1f(o);
  o = fmaf(a5, inv, bb1.y); hl[5] = o > 0.f ? o : expm1f(o);
  o = fmaf(a6, inv, bb1.z); hl[6] = o > 0.f ? o : expm1f(o);
  o = fmaf(a7, inv, bb1.w); hl[7] = o > 0.f ? o : expm1f(o);

  float oo[8];
#pragma unroll
  for (int k = 0; k < 8; ++k) {
    const float4* wp = (const float4*)(W2 + (size_t)k * 512 + cb);
    float4 w0 = wp[0], w1 = wp[1];
    oo[k] = hl[0] * w0.x + hl[1] * w0.y + hl[2] * w0.z + hl[3] * w0.w +
            hl[4] * w1.x + hl[5] * w1.y + hl[6] * w1.z + hl[7] * w1.w;
  }
#pragma unroll
  for (int ofs = 1; ofs < 64; ofs <<= 1) {
#pragma unroll
    for (int k = 0; k < 8; ++k) oo[k] += __shfl_xor(oo[k], ofs);
  }
  if (lane == 0) {
    float* ho = h2 + (size_t)n * 8;
#pragma unroll
    for (int k = 0; k < 8; ++k) ho[k] = oo[k];
#pragma unroll
    for (int h = 0; h < 4; ++h) {
      as2[(size_t)n * 4 + h] = oo[2 * h] * a_src2[2 * h] + oo[2 * h + 1] * a_src2[2 * h + 1];
      ad2[(size_t)n * 4 + h] = oo[2 * h] * a_dst2[2 * h] + oo[2 * h + 1] * a_dst2[2 * h + 1];
    }
  }
}

// ---------------- layer-2 softmax + aggregate + head-mean + bias ----------------
__global__ __launch_bounds__(256) void agg2_k(const float* __restrict__ h2,
                                              const float* __restrict__ as2,
                                              const float* __restrict__ ad2,
                                              const int* __restrict__ off,
                                              const int* __restrict__ csr,
                                              const float* __restrict__ b2,
                                              float* __restrict__ out, int N) {
  int n = blockIdx.x * 4 + (threadIdx.x >> 6);
  int lane = threadIdx.x & 63;
  if (n >= N) return;
  int row = off[n], end = off[n + 1];
  float4 adn = *(const float4*)(ad2 + (size_t)n * 4);

  float m0 = -1e30f, m1 = -1e30f, m2 = -1e30f, m3 = -1e30f;
  for (int idx = row + lane; idx < end; idx += 64) {
    int s = csr[idx];
    float4 av = *(const float4*)(as2 + (size_t)s * 4);
    float e0 = av.x + adn.x; e0 = e0 > 0.f ? e0 : NEG_SLOPE * e0; m0 = fmaxf(m0, e0);
    float e1 = av.y + adn.y; e1 = e1 > 0.f ? e1 : NEG_SLOPE * e1; m1 = fmaxf(m1, e1);
    float e2 = av.z + adn.z; e2 = e2 > 0.f ? e2 : NEG_SLOPE * e2; m2 = fmaxf(m2, e2);
    float e3 = av.w + adn.w; e3 = e3 > 0.f ? e3 : NEG_SLOPE * e3; m3 = fmaxf(m3, e3);
  }
#pragma unroll
  for (int ofs = 1; ofs < 64; ofs <<= 1) {
    m0 = fmaxf(m0, __shfl_xor(m0, ofs));
    m1 = fmaxf(m1, __shfl_xor(m1, ofs));
    m2 = fmaxf(m2, __shfl_xor(m2, ofs));
    m3 = fmaxf(m3, __shfl_xor(m3, ofs));
  }

  float z0 = 0.f, z1 = 0.f, z2 = 0.f, z3 = 0.f;
  float c0 = 0.f, c1 = 0.f, c2 = 0.f, c3 = 0.f, c4 = 0.f, c5 = 0.f, c6 = 0.f, c7 = 0.f;
  for (int idx = row + lane; idx < end; idx += 64) {
    int s = csr[idx];
    float4 av = *(const float4*)(as2 + (size_t)s * 4);
    const float4* vp = (const float4*)(h2 + (size_t)s * 8);
    float4 v0 = vp[0], v1 = vp[1];
    float e, p;
    e = av.x + adn.x; e = e > 0.f ? e : NEG_SLOPE * e; p = __expf(e - m0); z0 += p;
    c0 = fmaf(p, v0.x, c0); c1 = fmaf(p, v0.y, c1);
    e = av.y + adn.y; e = e > 0.f ? e : NEG_SLOPE * e; p = __expf(e - m1); z1 += p;
    c2 = fmaf(p, v0.z, c2); c3 = fmaf(p, v0.w, c3);
    e = av.z + adn.z; e = e > 0.f ? e : NEG_SLOPE * e; p = __expf(e - m2); z2 += p;
    c4 = fmaf(p, v1.x, c4); c5 = fmaf(p, v1.y, c5);
    e = av.w + adn.w; e = e > 0.f ? e : NEG_SLOPE * e; p = __expf(e - m3); z3 += p;
    c6 = fmaf(p, v1.z, c6); c7 = fmaf(p, v1.w, c7);
  }
#pragma unroll
  for (int ofs = 1; ofs < 64; ofs <<= 1) {
    z0 += __shfl_xor(z0, ofs); z1 += __shfl_xor(z1, ofs);
    z2 += __shfl_xor(z2, ofs); z3 += __shfl_xor(z3, ofs);
    c0 += __shfl_xor(c0, ofs); c1 += __shfl_xor(c1, ofs);
    c2 += __shfl_xor(c2, ofs); c3 += __shfl_xor(c3, ofs);
    c4 += __shfl_xor(c4, ofs); c5 += __shfl_xor(c5, ofs);
    c6 += __shfl_xor(c6, ofs); c7 += __shfl_xor(c7, ofs);
  }
  if (lane == 0) {
    float o0 = 0.25f * (c0 / z0 + c2 / z1 + c4 / z2 + c6 / z3) + b2[0];
    float o1 = 0.25f * (c1 / z0 + c3 / z1 + c5 / z2 + c7 / z3) + b2[1];
    out[(size_t)n * 2]     = o0;
    out[(size_t)n * 2 + 1] = o1;
  }
}

// ---------------- host ----------------
extern "C" void kernel_launch(void* const* d_in, const int* in_sizes, int n_in,
                              void* d_out, int out_size, void* d_ws, size_t ws_size,
                              hipStream_t stream) {
  const float* x      = (const float*)d_in[0];
  const int*   ei     = (const int*)d_in[1];
  const float* W1     = (const float*)d_in[2];
  const float* a_src1 = (const float*)d_in[3];
  const float* a_dst1 = (const float*)d_in[4];
  const float* b1     = (const float*)d_in[5];
  const float* W2     = (const float*)d_in[6];
  const float* a_src2 = (const float*)d_in[7];
  const float* a_dst2 = (const float*)d_in[8];
  const float* b2     = (const float*)d_in[9];
  float* out = (float*)d_out;

  const int N = in_sizes[0] / 128;
  const int E = in_sizes[1] / 2;
  const int TOT = E + N;

  char* ws = (char*)d_ws;
  auto alloc = [&](size_t bytes) {
    char* p = ws;
    ws += (bytes + 511) & ~(size_t)511;
    return p;
  };
  float* h1     = (float*)alloc((size_t)N * 512 * 4);
  float* as1ad1 = (float*)alloc((size_t)N * 8 * 4);   // as1 then ad1
  float* as1 = as1ad1;
  float* ad1 = as1ad1 + (size_t)N * 4;
  float* h2     = (float*)alloc((size_t)N * 8 * 4);
  float* as2    = (float*)alloc((size_t)N * 4 * 4);
  float* ad2    = (float*)alloc((size_t)N * 4 * 4);
  int*   deg    = (int*)alloc((size_t)N * 4);
  int*   off    = (int*)alloc((size_t)(N + 1) * 4);
  int*   cursor = (int*)alloc((size_t)N * 4);
  int*   csr    = (int*)alloc((size_t)TOT * 4);
  int*   sums   = (int*)alloc((size_t)1024 * 4);

  const int eb    = (TOT + 255) / 256;
  const int nb256 = (N + 255) / 256;     // also the scan1/scan3 grid
  const int nwb   = (N + 3) / 4;         // 4 waves (nodes) per 256-thread block

  hipMemsetAsync(deg, 0, (size_t)N * 4, stream);
  hipMemsetAsync(as1ad1, 0, (size_t)N * 8 * 4, stream);

  count_k<<<eb, 256, 0, stream>>>(ei, E, N, deg);
  scan1_k<<<nb256, 256, 0, stream>>>(deg, off, sums, N);
  scan2_k<<<1, 1024, 0, stream>>>(sums, nb256);
  scan3_k<<<nb256, 256, 0, stream>>>(off, sums, cursor, N, TOT);
  fill_k<<<eb, 256, 0, stream>>>(ei, E, N, cursor, csr);

  gemm1_k<<<dim3((N + 63) / 64, 512 / 64), 256, 0, stream>>>(x, W1, a_src1, a_dst1,
                                                             h1, as1, ad1, N);
  agg1_k<<<nwb, 256, 0, stream>>>(h1, as1, ad1, off, csr, b1,
                                  W2, a_src2, a_dst2, h2, as2, ad2, N);
  agg2_k<<<nwb, 256, 0, stream>>>(h2, as2, ad2, off, csr, b2, out, N);
}